// Round 11
// baseline (29.392 us; speedup 1.0000x reference)
//
#include <hip/hip_runtime.h>
#include <hip/hip_fp16.h>

// Problem constants (from reference setup_inputs)
constexpr int BAG       = 40;
constexpr int D         = 768;
constexpr int VOCAB     = 1276;
constexpr int AGE_DEPTH = 91;
constexpr int WROWS     = VOCAB + AGE_DEPTH;   // 1367

constexpr int COLS       = 16;                 // f16 cols per LDS slice
constexpr int NSLC       = D / COLS;           // 48 slices
constexpr int BANDS      = 20;                 // row-bands per slice
constexpr int GPB        = 2;                  // 192-row groups per band
constexpr int GROUP_ROWS = 192;                // rows per group (384 thr, 2/row)
constexpr int ROWS_A     = BANDS * GPB * GROUP_ROWS;  // 7680 rows via DS pipe
constexpr int TPB        = 512;                // waves 0-5: LDS path, 6-7: VMEM path
constexpr int NA         = 384;                // A-threads
constexpr int LDSU       = 2 * WROWS;          // 2734 uint4 = 43,744 B -> 3 blk/CU

typedef float fx4 __attribute__((ext_vector_type(4)));

__device__ __forceinline__ __half2 u2h(uint u) {
    union { uint u; __half2 h; } v; v.u = u; return v.h;
}
__device__ __forceinline__ ushort f2h(float f) {
    __half h = __float2half(f);     // RNE
    return *reinterpret_cast<ushort*>(&h);
}
__device__ __forceinline__ uint4 pack8(const float4 a, const float4 b) {
    uint4 p;
    p.x = (uint)f2h(a.x) | ((uint)f2h(a.y) << 16);
    p.y = (uint)f2h(a.z) | ((uint)f2h(a.w) << 16);
    p.z = (uint)f2h(b.x) | ((uint)f2h(b.y) << 16);
    p.w = (uint)f2h(b.z) | ((uint)f2h(b.w) << 16);
    return p;
}

// ---------------------------------------------------------------------------
// Fused dual-pipe kernel. Grid = 48 slices x 20 bands = 960 blocks.
// Waves 0-5 (384 thr): stage W[.,slice] f32->f16 in LDS ONCE, then gather
//   2 x 192-row groups from LDS (DS pipe). Persistent slice: staging cost
//   amortized over 384 rows.
// Waves 6-7: one wave per FULL row (rows >= ROWS_A), 41 coalesced 3KB f32
//   row-reads straight from L2 (VMEM pipe). Blocks 0..255 carry this work,
//   i.e. the first block dispatched on each CU -> both pipes busy per CU.
// ---------------------------------------------------------------------------
__global__ __launch_bounds__(TPB, 6) void embed_dual_kernel(
    const int* __restrict__ word,    // [rows, BAG]
    const int* __restrict__ age,     // [rows]
    const float* __restrict__ W,     // [WROWS, D] f32
    const float* __restrict__ bias,  // [D]
    float* __restrict__ out,         // [rows, D] f32
    int rows)
{
    __shared__ uint4 lds4[LDSU];

    const int bid   = blockIdx.x;
    const int slice = bid % NSLC;
    const int band  = bid / NSLC;
    const int c0    = slice * COLS;
    const int t     = threadIdx.x;

    // ---- A: stage slice (f32 -> f16, chunk-interleaved) ----
    if (t < NA) {
        #pragma unroll
        for (int k = 0; k < 8; ++k) {
            const int i = t + k * NA;
            if (i < LDSU) {
                const int r = i >> 1, u = i & 1;
                const float* src = W + (size_t)r * D + c0 + u * 8;
                const float4 a = *reinterpret_cast<const float4*>(src);
                const float4 b = *reinterpret_cast<const float4*>(src + 4);
                lds4[u * WROWS + r] = pack8(a, b);
            }
        }
    }
    __syncthreads();

    if (t < NA) {
        // ================= A: LDS gather path (DS pipe) =================
        const int rloc  = t >> 1;
        const int chunk = t & 1;
        const uint4* __restrict__ lp = lds4 + chunk * WROWS;
        const int c = c0 + chunk * 8;
        const float4 b0 = *reinterpret_cast<const float4*>(bias + c);
        const float4 b1 = *reinterpret_cast<const float4*>(bias + c + 4);

        #pragma unroll
        for (int gi = 0; gi < GPB; ++gi) {
            const int row = (band * GPB + gi) * GROUP_ROWS + rloc;
            const int* __restrict__ wrow = word + row * BAG;
            const int aidx = VOCAB + age[row];

            __half2 a0 = u2h(0u), a1 = u2h(0u), a2 = u2h(0u), a3 = u2h(0u);
            #pragma unroll
            for (int kb = 0; kb < 5; ++kb) {
                const int4 q0 = *reinterpret_cast<const int4*>(wrow + kb * 8);
                const int4 q1 = *reinterpret_cast<const int4*>(wrow + kb * 8 + 4);
                const int id[8] = {q0.x, q0.y, q0.z, q0.w, q1.x, q1.y, q1.z, q1.w};
                uint4 g[8];
                #pragma unroll
                for (int u = 0; u < 8; ++u) g[u] = lp[id[u]];
                #pragma unroll
                for (int u = 0; u < 8; ++u) {
                    a0 = __hadd2(a0, u2h(g[u].x));
                    a1 = __hadd2(a1, u2h(g[u].y));
                    a2 = __hadd2(a2, u2h(g[u].z));
                    a3 = __hadd2(a3, u2h(g[u].w));
                }
            }
            {
                const uint4 g = lp[aidx];
                a0 = __hadd2(a0, u2h(g.x));
                a1 = __hadd2(a1, u2h(g.y));
                a2 = __hadd2(a2, u2h(g.z));
                a3 = __hadd2(a3, u2h(g.w));
            }
            fx4 o0 = { b0.x + __low2float(a0), b0.y + __high2float(a0),
                       b0.z + __low2float(a1), b0.w + __high2float(a1) };
            fx4 o1 = { b1.x + __low2float(a2), b1.y + __high2float(a2),
                       b1.z + __low2float(a3), b1.w + __high2float(a3) };
            float* op = out + (size_t)row * D + c;
            __builtin_nontemporal_store(o0, reinterpret_cast<fx4*>(op));
            __builtin_nontemporal_store(o1, reinterpret_cast<fx4*>(op + 4));
        }
    } else {
        // ================= B: coalesced L2 gather path (VMEM pipe) ========
        const int w    = (t >> 6) - 6;          // 0..1
        const int lane = t & 63;
        const int slot = bid * 2 + w;
        const int row  = ROWS_A + slot;
        if (row < rows) {
            const int* __restrict__ wrow = word + row * BAG;
            const int aidx = VOCAB + age[row];
            const int cb = lane * 4;            // within each 256-col third

            float4 acc0 = *reinterpret_cast<const float4*>(bias + cb);
            float4 acc1 = *reinterpret_cast<const float4*>(bias + 256 + cb);
            float4 acc2 = *reinterpret_cast<const float4*>(bias + 512 + cb);

            #pragma unroll 4
            for (int j = 0; j < BAG; j += 2) {
                const int ia = wrow[j];
                const int ib = wrow[j + 1];
                const float* pa = W + (size_t)ia * D + cb;
                const float* pb = W + (size_t)ib * D + cb;
                const float4 a0 = *reinterpret_cast<const float4*>(pa);
                const float4 a1 = *reinterpret_cast<const float4*>(pa + 256);
                const float4 a2 = *reinterpret_cast<const float4*>(pa + 512);
                const float4 v0 = *reinterpret_cast<const float4*>(pb);
                const float4 v1 = *reinterpret_cast<const float4*>(pb + 256);
                const float4 v2 = *reinterpret_cast<const float4*>(pb + 512);
                acc0.x += a0.x + v0.x; acc0.y += a0.y + v0.y;
                acc0.z += a0.z + v0.z; acc0.w += a0.w + v0.w;
                acc1.x += a1.x + v1.x; acc1.y += a1.y + v1.y;
                acc1.z += a1.z + v1.z; acc1.w += a1.w + v1.w;
                acc2.x += a2.x + v2.x; acc2.y += a2.y + v2.y;
                acc2.z += a2.z + v2.z; acc2.w += a2.w + v2.w;
            }
            {
                const float* pa = W + (size_t)aidx * D + cb;
                const float4 a0 = *reinterpret_cast<const float4*>(pa);
                const float4 a1 = *reinterpret_cast<const float4*>(pa + 256);
                const float4 a2 = *reinterpret_cast<const float4*>(pa + 512);
                acc0.x += a0.x; acc0.y += a0.y; acc0.z += a0.z; acc0.w += a0.w;
                acc1.x += a1.x; acc1.y += a1.y; acc1.z += a1.z; acc1.w += a1.w;
                acc2.x += a2.x; acc2.y += a2.y; acc2.z += a2.z; acc2.w += a2.w;
            }
            float* op = out + (size_t)row * D + cb;
            fx4 o0 = {acc0.x, acc0.y, acc0.z, acc0.w};
            fx4 o1 = {acc1.x, acc1.y, acc1.z, acc1.w};
            fx4 o2 = {acc2.x, acc2.y, acc2.z, acc2.w};
            __builtin_nontemporal_store(o0, reinterpret_cast<fx4*>(op));
            __builtin_nontemporal_store(o1, reinterpret_cast<fx4*>(op + 256));
            __builtin_nontemporal_store(o2, reinterpret_cast<fx4*>(op + 512));
        }
    }
}

// ---------------------------------------------------------------------------
// Fallback (f32 direct gather) for any other shape.
// ---------------------------------------------------------------------------
__global__ __launch_bounds__(192) void embedbag_f32_kernel(
    const int* __restrict__ word, const int* __restrict__ age,
    const float* __restrict__ W, const float* __restrict__ bias,
    float* __restrict__ out)
{
    const int row = blockIdx.x;
    const int c   = threadIdx.x * 4;

    float4 acc = *reinterpret_cast<const float4*>(&bias[c]);
    const int* __restrict__ wrow = word + row * BAG;

    #pragma unroll 8
    for (int j = 0; j < BAG; ++j) {
        const int idx = wrow[j];
        const float4 v = *reinterpret_cast<const float4*>(&W[(size_t)idx * D + c]);
        acc.x += v.x; acc.y += v.y; acc.z += v.z; acc.w += v.w;
    }
    {
        const int idx = VOCAB + age[row];
        const float4 v = *reinterpret_cast<const float4*>(&W[(size_t)idx * D + c]);
        acc.x += v.x; acc.y += v.y; acc.z += v.z; acc.w += v.w;
    }
    *reinterpret_cast<float4*>(&out[(size_t)row * D + c]) = acc;
}

extern "C" void kernel_launch(void* const* d_in, const int* in_sizes, int n_in,
                              void* d_out, int out_size, void* d_ws, size_t ws_size,
                              hipStream_t stream) {
    const int* word   = (const int*)d_in[0];   // [B,S,BAG]
    const int* age    = (const int*)d_in[1];   // [B,S]
    const float* W    = (const float*)d_in[2]; // [WROWS, D]
    const float* bias = (const float*)d_in[3]; // [D]
    float* out        = (float*)d_out;         // [B,S,D]

    const int rows = in_sizes[1];              // B*S = 8192

    const int rows_b = rows - ROWS_A;          // 512 for rows=8192
    if (rows_b > 0 && rows_b <= 2 * NSLC * BANDS) {
        embed_dual_kernel<<<NSLC * BANDS, TPB, 0, stream>>>(
            word, age, W, bias, out, rows);
    } else {
        embedbag_f32_kernel<<<rows, D / 4, 0, stream>>>(word, age, W, bias, out);
    }
}

// Round 12
// 26.738 us; speedup vs baseline: 1.0993x; 1.0993x over previous
//
#include <hip/hip_runtime.h>
#include <hip/hip_fp16.h>

// Problem constants (from reference setup_inputs)
constexpr int BAG       = 40;
constexpr int D         = 768;
constexpr int VOCAB     = 1276;
constexpr int AGE_DEPTH = 91;
constexpr int WROWS     = VOCAB + AGE_DEPTH;   // 1367

constexpr int COLS   = 32;          // f16 columns staged per block
constexpr int NSLICE = D / COLS;    // 24 column slices
constexpr int RPB    = 256;         // rows per block (1 row per 4-lane group)
constexpr int TPB    = 1024;        // 16 waves; LDS 87.5KB -> 1 block/CU
constexpr int NCHUNK = COLS / 8;    // 4 chunks of 8 f16 (16B) per row
constexpr int LDSU   = NCHUNK * WROWS;  // 5468 uint4 = 87,488 B

// R5 champion (26.7us), restored as final kernel. Session record:
//   R5 26.7 | R6 3blk/CU 27.5 | R7 80B-pad layout 28.4 | R9 8-deep batch 31.6
//   R10 dbuf+idx-reuse 29.4 | R11 dual-pipe 29.4 | R8 hybrid 50.2 | R4 L2-only 33.2
// Diagnosis: bound by LDS random-gather crossbar service rate (~2x sequential
// ds_read_b128 cost) + serial stage phase; layout/occupancy/batching/pipelining
// all neutral. Bank conflicts measured negligible (R8: 0.13 extra cyc/read).

typedef float fx4 __attribute__((ext_vector_type(4)));

__device__ __forceinline__ __half2 u2h(uint u) {
    union { uint u; __half2 h; } v; v.u = u; return v.h;
}
__device__ __forceinline__ ushort f2h(float f) {
    __half h = __float2half(f);     // RNE
    return *reinterpret_cast<ushort*>(&h);
}

// ---------------------------------------------------------------------------
// One kernel: stage f32 W column-slice -> f16 in LDS, then gather-sum 41
// table rows per output row from LDS. No workspace, no convert pass.
// Grid: (rowblocks, NSLICE). Block: 1024 thr = 256 rows x 4 chunk-lanes.
// LDS layout: chunk-interleaved, entry (c,r) at lds4[c*WROWS + r].
// ---------------------------------------------------------------------------
__global__ __launch_bounds__(TPB) void embed_lds_kernel(
    const int* __restrict__ word,    // [ROWS, BAG]
    const int* __restrict__ age,     // [ROWS]
    const float* __restrict__ W,     // [WROWS, D] f32
    const float* __restrict__ bias,  // [D]
    float* __restrict__ out)         // [ROWS, D] f32
{
    __shared__ uint4 lds4[LDSU];

    const int rb    = blockIdx.x;          // row-block
    const int slice = blockIdx.y;          // column slice
    const int c0    = slice * COLS;

    // ---- stage: W[r, c0:c0+32] f32 -> f16, chunk-interleaved in LDS ----
    for (int s = threadIdx.x; s < LDSU; s += TPB) {
        const int r = s >> 2;              // table row
        const int u = s & 3;               // chunk (8 cols)
        const float* src = W + (size_t)r * D + c0 + u * 8;
        const float4 a = *reinterpret_cast<const float4*>(src);
        const float4 b = *reinterpret_cast<const float4*>(src + 4);
        uint4 p;
        p.x = (uint)f2h(a.x) | ((uint)f2h(a.y) << 16);
        p.y = (uint)f2h(a.z) | ((uint)f2h(a.w) << 16);
        p.z = (uint)f2h(b.x) | ((uint)f2h(b.y) << 16);
        p.w = (uint)f2h(b.z) | ((uint)f2h(b.w) << 16);
        lds4[u * WROWS + r] = p;
    }

    // ---- load this thread's row indices while staging loads are in flight
    const int t     = threadIdx.x;
    const int chunk = t & 3;               // which 8-col chunk of the slice
    const int rloc  = t >> 2;              // 0..255
    const int row   = rb * RPB + rloc;

    const int* __restrict__ wrow = word + row * BAG;   // 160B-aligned
    int idx[BAG];
    #pragma unroll
    for (int j = 0; j < BAG; j += 4) {
        const int4 q = *reinterpret_cast<const int4*>(wrow + j);
        idx[j] = q.x; idx[j + 1] = q.y; idx[j + 2] = q.z; idx[j + 3] = q.w;
    }
    const int aidx = VOCAB + age[row];

    __syncthreads();

    // ---- gather 41 rows from LDS, packed-f16 accumulate ----
    const uint4* __restrict__ lp = lds4 + chunk * WROWS;

    __half2 acc0 = u2h(0u), acc1 = u2h(0u), acc2 = u2h(0u), acc3 = u2h(0u);
    #pragma unroll
    for (int j = 0; j < BAG; ++j) {
        const uint4 g = lp[idx[j]];        // ds_read_b128
        acc0 = __hadd2(acc0, u2h(g.x));
        acc1 = __hadd2(acc1, u2h(g.y));
        acc2 = __hadd2(acc2, u2h(g.z));
        acc3 = __hadd2(acc3, u2h(g.w));
    }
    {
        const uint4 g = lp[aidx];
        acc0 = __hadd2(acc0, u2h(g.x));
        acc1 = __hadd2(acc1, u2h(g.y));
        acc2 = __hadd2(acc2, u2h(g.z));
        acc3 = __hadd2(acc3, u2h(g.w));
    }

    // ---- epilogue: f32 bias add, nontemporal 32B store ----
    const float* bp = bias + c0 + chunk * 8;
    const float4 b0 = *reinterpret_cast<const float4*>(bp);
    const float4 b1 = *reinterpret_cast<const float4*>(bp + 4);
    fx4 o0 = { b0.x + __low2float(acc0), b0.y + __high2float(acc0),
               b0.z + __low2float(acc1), b0.w + __high2float(acc1) };
    fx4 o1 = { b1.x + __low2float(acc2), b1.y + __high2float(acc2),
               b1.z + __low2float(acc3), b1.w + __high2float(acc3) };
    float* op = out + (size_t)row * D + c0 + chunk * 8;
    __builtin_nontemporal_store(o0, reinterpret_cast<fx4*>(op));
    __builtin_nontemporal_store(o1, reinterpret_cast<fx4*>(op + 4));
}

// ---------------------------------------------------------------------------
// Fallback (f32 direct gather) if rows isn't a multiple of RPB.
// ---------------------------------------------------------------------------
__global__ __launch_bounds__(192) void embedbag_f32_kernel(
    const int* __restrict__ word, const int* __restrict__ age,
    const float* __restrict__ W, const float* __restrict__ bias,
    float* __restrict__ out)
{
    const int row = blockIdx.x;
    const int c   = threadIdx.x * 4;

    float4 acc = *reinterpret_cast<const float4*>(&bias[c]);
    const int* __restrict__ wrow = word + row * BAG;

    #pragma unroll 8
    for (int j = 0; j < BAG; ++j) {
        const int idx = wrow[j];
        const float4 v = *reinterpret_cast<const float4*>(&W[(size_t)idx * D + c]);
        acc.x += v.x; acc.y += v.y; acc.z += v.z; acc.w += v.w;
    }
    {
        const int idx = VOCAB + age[row];
        const float4 v = *reinterpret_cast<const float4*>(&W[(size_t)idx * D + c]);
        acc.x += v.x; acc.y += v.y; acc.z += v.z; acc.w += v.w;
    }
    *reinterpret_cast<float4*>(&out[(size_t)row * D + c]) = acc;
}

extern "C" void kernel_launch(void* const* d_in, const int* in_sizes, int n_in,
                              void* d_out, int out_size, void* d_ws, size_t ws_size,
                              hipStream_t stream) {
    const int* word   = (const int*)d_in[0];   // [B,S,BAG]
    const int* age    = (const int*)d_in[1];   // [B,S]
    const float* W    = (const float*)d_in[2]; // [WROWS, D]
    const float* bias = (const float*)d_in[3]; // [D]
    float* out        = (float*)d_out;         // [B,S,D]

    const int rows = in_sizes[1];              // B*S = 8192

    if (rows % RPB == 0) {
        dim3 grid(rows / RPB, NSLICE);         // (32, 24) = 768 blocks
        embed_lds_kernel<<<grid, TPB, 0, stream>>>(word, age, W, bias, out);
    } else {
        embedbag_f32_kernel<<<rows, D / 4, 0, stream>>>(word, age, W, bias, out);
    }
}